// Round 7
// baseline (509.560 us; speedup 1.0000x reference)
//
#include <hip/hip_runtime.h>
#include <cstdint>

// ---- problem constants (MoEFeedForward: N=4096, D=1024, F=2048, E=8, top-2) ----
#define N_TOK 4096
#define D_MODEL 1024
#define D_FF 2048
#define D_GU 4096          // 2*D_FF: gate_up row space in wgu
#define N_EXP 8

typedef __bf16 bf16;
typedef __bf16 bf16x8 __attribute__((ext_vector_type(8)));
typedef float f32x4 __attribute__((ext_vector_type(4)));

typedef __attribute__((address_space(1))) void v1_t;
typedef __attribute__((address_space(3))) void v3_t;

// async global->LDS raw copy, 16B/lane; dest = wave-uniform base + lane*16
__device__ __forceinline__ void cp16(void* lds, const void* g) {
  __builtin_amdgcn_global_load_lds((v1_t*)g, (v3_t*)lds, 16, 0, 0);
}

__device__ __forceinline__ f32x4 mfma16(bf16x8 a, bf16x8 b, f32x4 c) {
  return __builtin_amdgcn_mfma_f32_16x16x32_bf16(a, b, c, 0, 0, 0);
}

__device__ __forceinline__ bf16x8 cvt8(float4 a, float4 b) {
  bf16x8 v;
  v[0] = (bf16)a.x; v[1] = (bf16)a.y; v[2] = (bf16)a.z; v[3] = (bf16)a.w;
  v[4] = (bf16)b.x; v[5] = (bf16)b.y; v[6] = (bf16)b.z; v[7] = (bf16)b.w;
  return v;
}

// ======== router: logits -> softmax -> top2 -> per-token meta; fuses x fp32->bf16 ========
__global__ __launch_bounds__(256) void router_kernel(
    const float* __restrict__ x, const float* __restrict__ wr,
    int* __restrict__ meta_e, float2* __restrict__ meta_p, bf16* __restrict__ xb)
{
  const int wave = threadIdx.x >> 6;
  const int lane = threadIdx.x & 63;

  for (int it = 0; it < 8; ++it) {
    const int token = blockIdx.x * 32 + it * 4 + wave;

    const float4* xrow = (const float4*)(x + (size_t)token * D_MODEL + lane * 16);
    float4 x0 = xrow[0], x1 = xrow[1], x2 = xrow[2], x3 = xrow[3];

    bf16* xd = xb + (size_t)token * D_MODEL + lane * 16;
    *(bf16x8*)xd       = cvt8(x0, x1);
    *(bf16x8*)(xd + 8) = cvt8(x2, x3);

    float logit[N_EXP];
#pragma unroll
    for (int e = 0; e < N_EXP; ++e) {
      const float4* wrow = (const float4*)(wr + e * D_MODEL + lane * 16);
      float4 w0 = wrow[0], w1 = wrow[1], w2 = wrow[2], w3 = wrow[3];
      float s = x0.x*w0.x + x0.y*w0.y + x0.z*w0.z + x0.w*w0.w
              + x1.x*w1.x + x1.y*w1.y + x1.z*w1.z + x1.w*w1.w
              + x2.x*w2.x + x2.y*w2.y + x2.z*w2.z + x2.w*w2.w
              + x3.x*w3.x + x3.y*w3.y + x3.z*w3.z + x3.w*w3.w;
#pragma unroll
      for (int m = 32; m >= 1; m >>= 1) s += __shfl_xor(s, m);
      logit[e] = fminf(fmaxf(s, -1e4f), 1e4f);    // reference CLAMP
    }

    if (lane == 0) {
      float mx = logit[0];
#pragma unroll
      for (int e = 1; e < N_EXP; ++e) mx = fmaxf(mx, logit[e]);
      float ex[N_EXP], sum = 0.f;
#pragma unroll
      for (int e = 0; e < N_EXP; ++e) { ex[e] = expf(logit[e] - mx); sum += ex[e]; }
      float p[N_EXP];
#pragma unroll
      for (int e = 0; e < N_EXP; ++e)
        p[e] = fminf(fmaxf(ex[e] / (sum + 1e-8f), 1e-8f), 1.0f);
      int e0 = 0;
#pragma unroll
      for (int e = 1; e < N_EXP; ++e) if (p[e] > p[e0]) e0 = e;
      int e1 = (e0 == 0) ? 1 : 0;
#pragma unroll
      for (int e = 0; e < N_EXP; ++e) if (e != e0 && p[e] > p[e1]) e1 = e;
      float p0 = p[e0], p1 = p[e1];
      float inv = 1.f / (p0 + p1 + 1e-8f);
      meta_e[token] = e0 | (e1 << 4);
      meta_p[token] = make_float2(p0 * inv, p1 * inv);
    }
  }
}

// ==== compact (block 0) + wgu cvt (blocks 1..2048) + wd cvt (blocks 2049..3072), ONE dispatch ====
__global__ __launch_bounds__(512) void compact_cvt_kernel(
    const int* __restrict__ meta_e, const float2* __restrict__ meta_p,
    int* __restrict__ counts, int* __restrict__ offsets,
    int* __restrict__ ids, float* __restrict__ wts,
    const float* __restrict__ wgu, bf16* __restrict__ wgub,
    const float* __restrict__ wd, bf16* __restrict__ wdb)
{
  if (blockIdx.x == 0) {
    __shared__ int lcnt[N_EXP], loff[N_EXP];
    const int lane = threadIdx.x & 63;
    const int e = threadIdx.x >> 6;          // wave = expert
    int c = 0;
    for (int ch = 0; ch < N_TOK / 64; ++ch) {
      int me = meta_e[ch * 64 + lane];
      bool pred = ((me & 15) == e) || (((me >> 4) & 15) == e);
      c += __popcll(__ballot(pred));
    }
    if (lane == 0) lcnt[e] = c;
    __syncthreads();
    if (threadIdx.x == 0) {
      int r = 0;
#pragma unroll
      for (int i = 0; i < N_EXP; ++i) {
        loff[i] = r; offsets[i] = r; counts[i] = lcnt[i]; r += lcnt[i];
      }
    }
    __syncthreads();
    int run = 0;
    for (int ch = 0; ch < N_TOK / 64; ++ch) {
      int t = ch * 64 + lane;
      int me = meta_e[t];
      bool is0 = ((me & 15) == e);
      bool pred = is0 || (((me >> 4) & 15) == e);
      unsigned long long mask = __ballot(pred);
      if (pred) {
        int li = run + __popcll(mask & ((1ull << lane) - 1ull));
        float2 p = meta_p[t];
        ids[e * N_TOK + li] = t;
        wts[e * N_TOK + li] = is0 ? p.x : p.y;
      }
      run += __popcll(mask);
    }
  } else if (blockIdx.x <= 2048) {
    const int n8 = (N_EXP * D_GU * D_MODEL) / 8;     // 4.19M items
    int i = (blockIdx.x - 1) * 512 + threadIdx.x;
    const int stride = 2048 * 512;
    for (; i < n8; i += stride) {
      const float4* s = (const float4*)wgu + 2 * (size_t)i;
      ((bf16x8*)wgub)[i] = cvt8(s[0], s[1]);
    }
  } else {
    const int n8 = (N_EXP * D_MODEL * D_FF) / 8;     // 2.10M items
    int i = (blockIdx.x - 2049) * 512 + threadIdx.x;
    const int stride = 1024 * 512;
    for (; i < n8; i += stride) {
      const float4* s = (const float4*)wd + 2 * (size_t)i;
      ((bf16x8*)wdb)[i] = cvt8(s[0], s[1]);
    }
  }
}

// ====== GEMM1s: fused SwiGLU, split-N dual-stream. Block tile: 128 rows x (64 gate + 64 up) ======
// per K-iter per thread: 4 cp16 + 8 ds_read_b128 + 16 MFMA (m97 inner-loop shape); 64 AGPR total
__global__ __launch_bounds__(256, 2) void gemm1s_kernel(
    const bf16* __restrict__ xb, const bf16* __restrict__ wgu,
    const int* __restrict__ counts, const int* __restrict__ offsets,
    const int* __restrict__ ids, bf16* __restrict__ H)
{
  const int e = blockIdx.z;
  const int cnt = counts[e];
  const int row0 = blockIdx.y * 128;
  if (row0 >= cnt) return;
  const int c0 = blockIdx.x * 64;            // hidden col tile in [0, 2048)

  __shared__ bf16 lA [128 * 32];             // 8 KB
  __shared__ bf16 lBg[64 * 32];              // 4 KB
  __shared__ bf16 lBu[64 * 32];              // 4 KB

  const int tid  = threadIdx.x;
  const int lane = tid & 63;
  const int wave = tid >> 6;
  const int l4 = lane >> 2;                  // row within 16-row chunk
  const int kb = (lane & 3) * 8;             // k offset (8 bf16 = 16B)

  const int ra0 = wave * 16 + l4;            // A rows (two chunks)
  const int ra1 = (wave + 4) * 16 + l4;
  const int rb  = wave * 16 + l4;            // B rows (one chunk of 64)

  const int* ide = ids + e * N_TOK;
  const int m0 = min(row0 + ra0, cnt - 1);
  const int m1 = min(row0 + ra1, cnt - 1);
  const bf16* srcA0 = xb + (size_t)ide[m0] * D_MODEL + kb;
  const bf16* srcA1 = xb + (size_t)ide[m1] * D_MODEL + kb;
  const bf16* wge = wgu + (size_t)e * D_GU * D_MODEL;
  const bf16* srcG = wge + (size_t)(c0 + rb) * D_MODEL + kb;          // gate rows
  const bf16* srcU = wge + (size_t)(D_FF + c0 + rb) * D_MODEL + kb;   // up rows

  char* dA0 = (char*)lA  + wave * 1024;
  char* dA1 = (char*)lA  + (wave + 4) * 1024;
  char* dG  = (char*)lBg + wave * 1024;
  char* dU  = (char*)lBu + wave * 1024;

  const int wm = wave >> 1;                  // row half (0/1) -> 64 rows
  const int wn = wave & 1;                   // col half (0/1) -> 32 cols
  const int fr = lane & 15;
  const int fq = lane >> 4;
  const bf16* pA = lA  + (wm * 64 + fr) * 32 + fq * 8;
  const bf16* pG = lBg + (wn * 32 + fr) * 32 + fq * 8;
  const bf16* pU = lBu + (wn * 32 + fr) * 32 + fq * 8;

  f32x4 accg[4][2], accu[4][2];
#pragma unroll
  for (int i = 0; i < 4; ++i)
#pragma unroll
    for (int j = 0; j < 2; ++j)
#pragma unroll
      for (int k = 0; k < 4; ++k) { accg[i][j][k] = 0.f; accu[i][j][k] = 0.f; }

  for (int kt = 0; kt < D_MODEL / 32; ++kt) {
    cp16(dA0, srcA0); cp16(dA1, srcA1);
    cp16(dG, srcG);   cp16(dU, srcU);
    srcA0 += 32; srcA1 += 32; srcG += 32; srcU += 32;
    __syncthreads();
    bf16x8 a[4];
#pragma unroll
    for (int fm = 0; fm < 4; ++fm) a[fm] = *(const bf16x8*)(pA + fm * 16 * 32);
#pragma unroll
    for (int fn = 0; fn < 2; ++fn) {
      bf16x8 bg = *(const bf16x8*)(pG + fn * 16 * 32);
      bf16x8 bu = *(const bf16x8*)(pU + fn * 16 * 32);
#pragma unroll
      for (int fm = 0; fm < 4; ++fm) {
        accg[fm][fn] = mfma16(a[fm], bg, accg[fm][fn]);
        accu[fm][fn] = mfma16(a[fm], bu, accu[fm][fn]);
      }
    }
    __syncthreads();
  }

  const int hbase = offsets[e] + row0;
#pragma unroll
  for (int fm = 0; fm < 4; ++fm) {
#pragma unroll
    for (int fn = 0; fn < 2; ++fn) {
#pragma unroll
      for (int i = 0; i < 4; ++i) {
        int m = wm * 64 + fm * 16 + fq * 4 + i;   // C/D: row = quad*4+reg
        if (row0 + m < cnt) {
          float g = accg[fm][fn][i];
          float u = accu[fm][fn][i];
          float h = g * u / (1.f + expf(-u));     // gate * silu(up)
          int col = c0 + wn * 32 + fn * 16 + fr;  // C/D: col = lane&15
          H[(size_t)(hbase + m) * D_FF + col] = (bf16)h;
        }
      }
    }
  }
}

// ====== GEMM2: H(bf16, pitch 2048) @ Wd_b^T -> atomicAdd(w*acc) into fp32 out ======
__global__ __launch_bounds__(256, 2) void gemm2_kernel(
    const bf16* __restrict__ H, const bf16* __restrict__ wdb,
    const int* __restrict__ counts, const int* __restrict__ offsets,
    const int* __restrict__ ids, const float* __restrict__ wts,
    float* __restrict__ out)
{
  const int e = blockIdx.z;
  const int cnt = counts[e];
  const int row0 = blockIdx.y * 128;
  if (row0 >= cnt) return;
  const int c0 = blockIdx.x * 128;           // output col tile in [0, 1024)
  const int base = offsets[e];

  __shared__ bf16 lA[128 * 32];
  __shared__ bf16 lB[128 * 32];

  const int tid  = threadIdx.x;
  const int lane = tid & 63;
  const int wave = tid >> 6;
  const int l4 = lane >> 2;
  const int kb = (lane & 3) * 8;

  const int ra0 = wave * 16 + l4;
  const int ra1 = (wave + 4) * 16 + l4;
  const int m0 = min(row0 + ra0, cnt - 1);
  const int m1 = min(row0 + ra1, cnt - 1);
  const bf16* srcA0 = H + (size_t)(base + m0) * D_FF + kb;
  const bf16* srcA1 = H + (size_t)(base + m1) * D_FF + kb;
  const bf16* wde = wdb + (size_t)e * D_MODEL * D_FF;
  const bf16* srcB0 = wde + (size_t)(c0 + ra0) * D_FF + kb;
  const bf16* srcB1 = wde + (size_t)(c0 + ra1) * D_FF + kb;

  char* dA0 = (char*)lA + wave * 1024;
  char* dA1 = (char*)lA + (wave + 4) * 1024;
  char* dB0 = (char*)lB + wave * 1024;
  char* dB1 = (char*)lB + (wave + 4) * 1024;

  const int wm = wave >> 1;
  const int wn = wave & 1;
  const int fr = lane & 15;
  const int fq = lane >> 4;
  const bf16* pA = lA + (wm * 64 + fr) * 32 + fq * 8;
  const bf16* pB = lB + (wn * 64 + fr) * 32 + fq * 8;

  f32x4 acc[4][4];
#pragma unroll
  for (int i = 0; i < 4; ++i)
#pragma unroll
    for (int j = 0; j < 4; ++j)
#pragma unroll
      for (int k = 0; k < 4; ++k) acc[i][j][k] = 0.f;

  for (int kt = 0; kt < D_FF / 32; ++kt) {
    cp16(dA0, srcA0); cp16(dA1, srcA1);
    cp16(dB0, srcB0); cp16(dB1, srcB1);
    srcA0 += 32; srcA1 += 32; srcB0 += 32; srcB1 += 32;
    __syncthreads();
    bf16x8 a[4];
#pragma unroll
    for (int fm = 0; fm < 4; ++fm) a[fm] = *(const bf16x8*)(pA + fm * 16 * 32);
#pragma unroll
    for (int fn = 0; fn < 4; ++fn) {
      bf16x8 b = *(const bf16x8*)(pB + fn * 16 * 32);
#pragma unroll
      for (int fm = 0; fm < 4; ++fm) acc[fm][fn] = mfma16(a[fm], b, acc[fm][fn]);
    }
    __syncthreads();
  }

  const int* ide = ids + e * N_TOK;
  const float* wte = wts + e * N_TOK;
#pragma unroll
  for (int fm = 0; fm < 4; ++fm) {
#pragma unroll
    for (int i = 0; i < 4; ++i) {
      int m = wm * 64 + fm * 16 + fq * 4 + i;
      if (row0 + m < cnt) {
        int   tok = ide[row0 + m];
        float w   = wte[row0 + m];
        float* orow = out + (size_t)tok * D_MODEL;
#pragma unroll
        for (int fn = 0; fn < 4; ++fn) {
          int col = c0 + wn * 64 + fn * 16 + fr;
          atomicAdd(orow + col, w * acc[fm][fn][i]);
        }
      }
    }
  }
}

// =========================================================================================
extern "C" void kernel_launch(void* const* d_in, const int* in_sizes, int n_in,
                              void* d_out, int out_size, void* d_ws, size_t ws_size,
                              hipStream_t stream) {
  const float* x   = (const float*)d_in[0];
  const float* wr  = (const float*)d_in[1];
  const float* wgu = (const float*)d_in[2];
  const float* wd  = (const float*)d_in[3];
  float* out = (float*)d_out;

  char* ws = (char*)d_ws;
  // workspace layout — 136.5 MB total (proven available in rounds 4-6)
  int*    counts  = (int*)ws;                        // 32 B
  int*    offsets = (int*)(ws + 64);                 // 32 B
  int*    meta_e  = (int*)(ws + 1024);               // 16 KB
  float2* meta_p  = (float2*)(ws + 32768);           // 32 KB
  int*    ids     = (int*)(ws + 131072);             // 128 KB
  float*  wts     = (float*)(ws + 262144);           // 128 KB
  bf16*   xb      = (bf16*)(ws + 524288);            // 8 MB
  bf16*   wgub    = (bf16*)(ws + 524288 + 8388608);                    // 64 MB
  bf16*   wdb     = (bf16*)(ws + 524288 + 8388608 + 67108864);         // 32 MB
  bf16*   H       = (bf16*)(ws + 524288 + 8388608 + 67108864 + 33554432); // 32 MB

  hipMemsetAsync(out, 0, (size_t)N_TOK * D_MODEL * sizeof(float), stream);
  router_kernel<<<N_TOK / 32, 256, 0, stream>>>(x, wr, meta_e, meta_p, xb);
  compact_cvt_kernel<<<3073, 512, 0, stream>>>(
      meta_e, meta_p, counts, offsets, ids, wts, wgu, wgub, wd, wdb);
  gemm1s_kernel<<<dim3(D_FF / 64, N_TOK / 128, N_EXP), 256, 0, stream>>>(
      xb, wgub, counts, offsets, ids, H);
  gemm2_kernel<<<dim3(D_MODEL / 128, N_TOK / 128, N_EXP), 256, 0, stream>>>(
      H, wdb, counts, offsets, ids, wts, out);
}

// Round 8
// 494.223 us; speedup vs baseline: 1.0310x; 1.0310x over previous
//
#include <hip/hip_runtime.h>
#include <cstdint>

// ---- problem constants (MoEFeedForward: N=4096, D=1024, F=2048, E=8, top-2) ----
#define N_TOK 4096
#define D_MODEL 1024
#define D_FF 2048
#define D_GU 4096          // 2*D_FF: gate_up row space in wgu
#define N_EXP 8
#define PITCH 40           // padded LDS pitch for cvt-staged B tiles

typedef __bf16 bf16;
typedef __bf16 bf16x8 __attribute__((ext_vector_type(8)));
typedef float f32x4 __attribute__((ext_vector_type(4)));

typedef __attribute__((address_space(1))) void v1_t;
typedef __attribute__((address_space(3))) void v3_t;

// async global->LDS raw copy, 16B/lane; dest = wave-uniform base + lane*16
__device__ __forceinline__ void cp16(void* lds, const void* g) {
  __builtin_amdgcn_global_load_lds((v1_t*)g, (v3_t*)lds, 16, 0, 0);
}

__device__ __forceinline__ f32x4 mfma16(bf16x8 a, bf16x8 b, f32x4 c) {
  return __builtin_amdgcn_mfma_f32_16x16x32_bf16(a, b, c, 0, 0, 0);
}

__device__ __forceinline__ bf16x8 cvt8(float4 a, float4 b) {
  bf16x8 v;
  v[0] = (bf16)a.x; v[1] = (bf16)a.y; v[2] = (bf16)a.z; v[3] = (bf16)a.w;
  v[4] = (bf16)b.x; v[5] = (bf16)b.y; v[6] = (bf16)b.z; v[7] = (bf16)b.w;
  return v;
}

// ======== router: logits -> softmax -> top2 -> compacted expert lists (LDS-agg atomics);
// ======== fuses x fp32->bf16. 32 tokens/block.
__global__ __launch_bounds__(256) void router_kernel(
    const float* __restrict__ x, const float* __restrict__ wr,
    int* __restrict__ counts, int* __restrict__ ids, float* __restrict__ wts,
    bf16* __restrict__ xb)
{
  __shared__ int lcnt[N_EXP];
  __shared__ int gbase[N_EXP];
  __shared__ int s_e0[32], s_l0[32], s_e1[32], s_l1[32];
  __shared__ float s_p0[32], s_p1[32];

  const int tid  = threadIdx.x;
  const int wave = tid >> 6;
  const int lane = tid & 63;
  if (tid < N_EXP) lcnt[tid] = 0;
  __syncthreads();

  for (int it = 0; it < 8; ++it) {
    const int li = it * 4 + wave;
    const int token = blockIdx.x * 32 + li;

    const float4* xrow = (const float4*)(x + (size_t)token * D_MODEL + lane * 16);
    float4 x0 = xrow[0], x1 = xrow[1], x2 = xrow[2], x3 = xrow[3];

    bf16* xd = xb + (size_t)token * D_MODEL + lane * 16;
    *(bf16x8*)xd       = cvt8(x0, x1);
    *(bf16x8*)(xd + 8) = cvt8(x2, x3);

    float logit[N_EXP];
#pragma unroll
    for (int e = 0; e < N_EXP; ++e) {
      const float4* wrow = (const float4*)(wr + e * D_MODEL + lane * 16);
      float4 w0 = wrow[0], w1 = wrow[1], w2 = wrow[2], w3 = wrow[3];
      float s = x0.x*w0.x + x0.y*w0.y + x0.z*w0.z + x0.w*w0.w
              + x1.x*w1.x + x1.y*w1.y + x1.z*w1.z + x1.w*w1.w
              + x2.x*w2.x + x2.y*w2.y + x2.z*w2.z + x2.w*w2.w
              + x3.x*w3.x + x3.y*w3.y + x3.z*w3.z + x3.w*w3.w;
#pragma unroll
      for (int m = 32; m >= 1; m >>= 1) s += __shfl_xor(s, m);
      logit[e] = fminf(fmaxf(s, -1e4f), 1e4f);    // reference CLAMP
    }

    if (lane == 0) {
      float mx = logit[0];
#pragma unroll
      for (int e = 1; e < N_EXP; ++e) mx = fmaxf(mx, logit[e]);
      float ex[N_EXP], sum = 0.f;
#pragma unroll
      for (int e = 0; e < N_EXP; ++e) { ex[e] = expf(logit[e] - mx); sum += ex[e]; }
      float p[N_EXP];
#pragma unroll
      for (int e = 0; e < N_EXP; ++e)
        p[e] = fminf(fmaxf(ex[e] / (sum + 1e-8f), 1e-8f), 1.0f);
      int e0 = 0;
#pragma unroll
      for (int e = 1; e < N_EXP; ++e) if (p[e] > p[e0]) e0 = e;
      int e1 = (e0 == 0) ? 1 : 0;
#pragma unroll
      for (int e = 0; e < N_EXP; ++e) if (e != e0 && p[e] > p[e1]) e1 = e;
      float p0 = p[e0], p1 = p[e1];
      float inv = 1.f / (p0 + p1 + 1e-8f);
      s_e0[li] = e0; s_l0[li] = atomicAdd(&lcnt[e0], 1); s_p0[li] = p0 * inv;
      s_e1[li] = e1; s_l1[li] = atomicAdd(&lcnt[e1], 1); s_p1[li] = p1 * inv;
    }
  }
  __syncthreads();
  if (tid < N_EXP) gbase[tid] = atomicAdd(&counts[tid], lcnt[tid]);
  __syncthreads();
  if (tid < 32) {
    const int token = blockIdx.x * 32 + tid;
    int e0 = s_e0[tid], e1 = s_e1[tid];
    int a = gbase[e0] + s_l0[tid];
    int b = gbase[e1] + s_l1[tid];
    ids[e0 * N_TOK + a] = token; wts[e0 * N_TOK + a] = s_p0[tid];
    ids[e1 * N_TOK + b] = token; wts[e1 * N_TOK + b] = s_p1[tid];
  }
}

// ====== GEMM1s-cvt: fused SwiGLU; A=cp16(xb bf16), B=wgu fp32 cvt-staged in-loop ======
// block tile: 128 rows x (64 gate + 64 up cols); 16 MFMA/K-iter; 64 AGPR
__global__ __launch_bounds__(256, 2) void gemm1s_kernel(
    const bf16* __restrict__ xb, const float* __restrict__ wgu,
    const int* __restrict__ counts, const int* __restrict__ ids,
    bf16* __restrict__ H)
{
  const int e = blockIdx.z;
  const int cnt = counts[e];
  const int row0 = blockIdx.y * 128;
  if (row0 >= cnt) return;
  const int c0 = blockIdx.x * 64;            // hidden col tile in [0, 2048)

  int hoff = 0;                               // offsets[e] computed locally
  for (int i = 0; i < N_EXP; ++i) hoff += (i < e) ? counts[i] : 0;

  __shared__ bf16 lA [128 * 32];             // 8 KB, cp16 (pitch 32)
  __shared__ bf16 lBg[64 * PITCH];           // 5 KB, cvt-staged (pitch 40)
  __shared__ bf16 lBu[64 * PITCH];           // 5 KB

  const int tid  = threadIdx.x;
  const int lane = tid & 63;
  const int wave = tid >> 6;
  const int l4 = lane >> 2;
  const int kb = (lane & 3) * 8;

  const int ra0 = wave * 16 + l4;
  const int ra1 = (wave + 4) * 16 + l4;

  const int* ide = ids + e * N_TOK;
  const int m0 = min(row0 + ra0, cnt - 1);
  const int m1 = min(row0 + ra1, cnt - 1);
  const bf16* srcA0 = xb + (size_t)ide[m0] * D_MODEL + kb;
  const bf16* srcA1 = xb + (size_t)ide[m1] * D_MODEL + kb;

  // B staging map: 64 rows x 32 k in one issue; thread -> (sr, 8 fp32 at sk)
  const int sr = tid >> 2;                   // 0..63
  const int sk = (tid & 3) * 8;
  const float* wge = wgu + (size_t)e * D_GU * D_MODEL;
  const float* pg = wge + (size_t)(c0 + sr) * D_MODEL + sk;           // gate row
  const float* pu = wge + (size_t)(D_FF + c0 + sr) * D_MODEL + sk;    // up row

  char* dA0 = (char*)lA + wave * 1024;
  char* dA1 = (char*)lA + (wave + 4) * 1024;
  bf16* wG = lBg + sr * PITCH + sk;
  bf16* wU = lBu + sr * PITCH + sk;

  const int wm = wave >> 1;                  // row half
  const int wn = wave & 1;                   // col half (32 cols each)
  const int fr = lane & 15;
  const int fq = lane >> 4;
  const bf16* pA = lA  + (wm * 64 + fr) * 32 + fq * 8;
  const bf16* pG = lBg + (wn * 32 + fr) * PITCH + fq * 8;
  const bf16* pU = lBu + (wn * 32 + fr) * PITCH + fq * 8;

  f32x4 accg[4][2], accu[4][2];
#pragma unroll
  for (int i = 0; i < 4; ++i)
#pragma unroll
    for (int j = 0; j < 2; ++j)
#pragma unroll
      for (int k = 0; k < 4; ++k) { accg[i][j][k] = 0.f; accu[i][j][k] = 0.f; }

  for (int kt = 0; kt < D_MODEL / 32; ++kt) {
    float4 g0 = *(const float4*)pg, g1 = *(const float4*)(pg + 4);
    float4 u0 = *(const float4*)pu, u1 = *(const float4*)(pu + 4);
    cp16(dA0, srcA0); cp16(dA1, srcA1);
    srcA0 += 32; srcA1 += 32; pg += 32; pu += 32;
    // prev iter's trailing barrier guarantees LDS free for overwrite
    *(bf16x8*)wG = cvt8(g0, g1);
    *(bf16x8*)wU = cvt8(u0, u1);
    __syncthreads();   // staging visible (drains vmcnt for cp16 + lgkm for ds_write)
    bf16x8 a[4];
#pragma unroll
    for (int fm = 0; fm < 4; ++fm) a[fm] = *(const bf16x8*)(pA + fm * 16 * 32);
#pragma unroll
    for (int fn = 0; fn < 2; ++fn) {
      bf16x8 bg = *(const bf16x8*)(pG + fn * 16 * PITCH);
      bf16x8 bu = *(const bf16x8*)(pU + fn * 16 * PITCH);
#pragma unroll
      for (int fm = 0; fm < 4; ++fm) {
        accg[fm][fn] = mfma16(a[fm], bg, accg[fm][fn]);
        accu[fm][fn] = mfma16(a[fm], bu, accu[fm][fn]);
      }
    }
    __syncthreads();   // LDS reads done before next overwrite
  }

  const int hbase = hoff + row0;
#pragma unroll
  for (int fm = 0; fm < 4; ++fm) {
#pragma unroll
    for (int fn = 0; fn < 2; ++fn) {
#pragma unroll
      for (int i = 0; i < 4; ++i) {
        int m = wm * 64 + fm * 16 + fq * 4 + i;   // C/D: row = quad*4+reg
        if (row0 + m < cnt) {
          float g = accg[fm][fn][i];
          float u = accu[fm][fn][i];
          float h = g * u / (1.f + expf(-u));     // gate * silu(up)
          int col = c0 + wn * 32 + fn * 16 + fr;  // C/D: col = lane&15
          H[(size_t)(hbase + m) * D_FF + col] = (bf16)h;
        }
      }
    }
  }
}

// ====== GEMM2-cvt: A=cp16(H bf16), B=wd fp32 cvt-staged; atomicAdd(w*acc) into fp32 out ======
__global__ __launch_bounds__(256, 2) void gemm2_kernel(
    const bf16* __restrict__ H, const float* __restrict__ wd,
    const int* __restrict__ counts, const int* __restrict__ ids,
    const float* __restrict__ wts, float* __restrict__ out)
{
  const int e = blockIdx.z;
  const int cnt = counts[e];
  const int row0 = blockIdx.y * 128;
  if (row0 >= cnt) return;
  const int c0 = blockIdx.x * 128;           // output col tile in [0, 1024)

  int base = 0;
  for (int i = 0; i < N_EXP; ++i) base += (i < e) ? counts[i] : 0;

  __shared__ bf16 lA[128 * 32];              // cp16 (pitch 32)
  __shared__ bf16 lB[128 * PITCH];           // cvt-staged (pitch 40)

  const int tid  = threadIdx.x;
  const int lane = tid & 63;
  const int wave = tid >> 6;
  const int l4 = lane >> 2;
  const int kb = (lane & 3) * 8;

  const int ra0 = wave * 16 + l4;
  const int ra1 = (wave + 4) * 16 + l4;
  const int m0 = min(row0 + ra0, cnt - 1);
  const int m1 = min(row0 + ra1, cnt - 1);
  const bf16* srcA0 = H + (size_t)(base + m0) * D_FF + kb;
  const bf16* srcA1 = H + (size_t)(base + m1) * D_FF + kb;

  const int sr = tid >> 2;                   // B: 128 rows in two issues
  const int sk = (tid & 3) * 8;
  const float* wde = wd + (size_t)e * D_MODEL * D_FF;
  const float* pb0 = wde + (size_t)(c0 + sr) * D_FF + sk;
  const float* pb1 = wde + (size_t)(c0 + sr + 64) * D_FF + sk;

  char* dA0 = (char*)lA + wave * 1024;
  char* dA1 = (char*)lA + (wave + 4) * 1024;
  bf16* wB0 = lB + sr * PITCH + sk;
  bf16* wB1 = lB + (sr + 64) * PITCH + sk;

  const int wm = wave >> 1;
  const int wn = wave & 1;
  const int fr = lane & 15;
  const int fq = lane >> 4;
  const bf16* pA = lA + (wm * 64 + fr) * 32 + fq * 8;
  const bf16* pB = lB + (wn * 64 + fr) * PITCH + fq * 8;

  f32x4 acc[4][4];
#pragma unroll
  for (int i = 0; i < 4; ++i)
#pragma unroll
    for (int j = 0; j < 4; ++j)
#pragma unroll
      for (int k = 0; k < 4; ++k) acc[i][j][k] = 0.f;

  for (int kt = 0; kt < D_FF / 32; ++kt) {
    float4 b00 = *(const float4*)pb0, b01 = *(const float4*)(pb0 + 4);
    float4 b10 = *(const float4*)pb1, b11 = *(const float4*)(pb1 + 4);
    cp16(dA0, srcA0); cp16(dA1, srcA1);
    srcA0 += 32; srcA1 += 32; pb0 += 32; pb1 += 32;
    *(bf16x8*)wB0 = cvt8(b00, b01);
    *(bf16x8*)wB1 = cvt8(b10, b11);
    __syncthreads();
    bf16x8 a[4];
#pragma unroll
    for (int fm = 0; fm < 4; ++fm) a[fm] = *(const bf16x8*)(pA + fm * 16 * 32);
#pragma unroll
    for (int fn = 0; fn < 4; ++fn) {
      bf16x8 b = *(const bf16x8*)(pB + fn * 16 * PITCH);
#pragma unroll
      for (int fm = 0; fm < 4; ++fm) acc[fm][fn] = mfma16(a[fm], b, acc[fm][fn]);
    }
    __syncthreads();
  }

  const int* ide = ids + e * N_TOK;
  const float* wte = wts + e * N_TOK;
#pragma unroll
  for (int fm = 0; fm < 4; ++fm) {
#pragma unroll
    for (int i = 0; i < 4; ++i) {
      int m = wm * 64 + fm * 16 + fq * 4 + i;
      if (row0 + m < cnt) {
        int   tok = ide[row0 + m];
        float w   = wte[row0 + m];
        float* orow = out + (size_t)tok * D_MODEL;
#pragma unroll
        for (int fn = 0; fn < 4; ++fn) {
          int col = c0 + wn * 64 + fn * 16 + fr;
          atomicAdd(orow + col, w * acc[fm][fn][i]);
        }
      }
    }
  }
}

// =========================================================================================
extern "C" void kernel_launch(void* const* d_in, const int* in_sizes, int n_in,
                              void* d_out, int out_size, void* d_ws, size_t ws_size,
                              hipStream_t stream) {
  const float* x   = (const float*)d_in[0];
  const float* wr  = (const float*)d_in[1];
  const float* wgu = (const float*)d_in[2];
  const float* wd  = (const float*)d_in[3];
  float* out = (float*)d_out;

  char* ws = (char*)d_ws;
  // workspace layout — ~41 MB total (no weight conversion buffers)
  int*   counts = (int*)ws;                          // 64 B
  int*   ids    = (int*)(ws + 4096);                 // 128 KB
  float* wts    = (float*)(ws + 4096 + 131072);      // 128 KB
  bf16*  xb     = (bf16*)(ws + 524288);              // 8 MB
  bf16*  H      = (bf16*)(ws + 524288 + 8388608);    // 32 MB (8192 x 2048 bf16)

  hipMemsetAsync(counts, 0, 64, stream);
  hipMemsetAsync(out, 0, (size_t)N_TOK * D_MODEL * sizeof(float), stream);
  router_kernel<<<N_TOK / 32, 256, 0, stream>>>(x, wr, counts, ids, wts, xb);
  gemm1s_kernel<<<dim3(D_FF / 64, N_TOK / 128, N_EXP), 256, 0, stream>>>(
      xb, wgu, counts, ids, H);
  gemm2_kernel<<<dim3(D_MODEL / 128, N_TOK / 128, N_EXP), 256, 0, stream>>>(
      H, wd, counts, ids, wts, out);
}